// Round 10
// baseline (612.577 us; speedup 1.0000x reference)
//
#include <hip/hip_runtime.h>
#include <hip/hip_fp16.h>

#define NN 100000
#define NE 3200000
#define H  64

#define SCAN_BLOCK 256
#define SCAN_ITEMS 4
#define SCAN_TILE  1024
#define NB1 ((NN + SCAN_TILE - 1) / SCAN_TILE)   // 98

#define BSHIFT 7
#define BNODES 128
#define NB ((NN + BNODES - 1) / BNODES)          // 782 partition buckets

#define PTHREADS 1024
#define PCHUNK   8192
#define PEPT     (PCHUNK / PTHREADS)             // 8
#define NPBLK    ((NE + PCHUNK - 1) / PCHUNK)    // 391

#define GCAP 2560                                // per-half-bucket edge cap (mean 2048, sd ~45)

// ---------------- encoder + fused edge count (verified R6/R9) ----------------
__global__ __launch_bounds__(256) void encoder_count_kernel(
    const float* __restrict__ x,
    const float* __restrict__ W1, const float* __restrict__ b1,
    const float* __restrict__ W2, const float* __restrict__ b2,
    const int* __restrict__ src, int* __restrict__ counts,
    __half* __restrict__ h16)
{
    __shared__ float sh1[4][H];
    const int tid  = threadIdx.x;
    const int slot = tid >> 6;
    const int f    = tid & 63;
    const int node = blockIdx.x * 4 + slot;      // grid 25000 -> node < NN always

    const int e = blockIdx.x * 256 + tid;        // 6.4M threads cover NE
    if (e < NE) atomicAdd(&counts[src[e]], 1);

    {
        float acc = b1[f];
        #pragma unroll
        for (int k = 0; k < 6; ++k)
            acc = fmaf(x[node * 6 + k], W1[k * H + f], acc);
        sh1[slot][f] = fmaxf(acc, 0.0f);
    }
    __syncthreads();
    {
        float acc = b2[f];
        #pragma unroll 8
        for (int k = 0; k < H; ++k)
            acc = fmaf(sh1[slot][k], W2[k * H + f], acc);
        h16[node * H + f] = __float2half(acc);
    }
}

// ---------------- scan stage 1 (verified R6/R9) ----------------
__global__ __launch_bounds__(256) void scan1_kernel(
    const int* __restrict__ counts, int* __restrict__ offs, int* __restrict__ partials)
{
    __shared__ int s[SCAN_BLOCK];
    const int t = threadIdx.x, bid = blockIdx.x;
    const int base = bid * SCAN_TILE + t * SCAN_ITEMS;
    int v[SCAN_ITEMS];
    int sum = 0;
    #pragma unroll
    for (int j = 0; j < SCAN_ITEMS; ++j) {
        const int i = base + j;
        v[j] = (i < NN) ? counts[i] : 0;
        sum += v[j];
    }
    s[t] = sum;
    __syncthreads();
    for (int off = 1; off < SCAN_BLOCK; off <<= 1) {
        int xv = 0;
        if (t >= off) xv = s[t - off];
        __syncthreads();
        if (t >= off) s[t] += xv;
        __syncthreads();
    }
    int excl = s[t] - sum;
    #pragma unroll
    for (int j = 0; j < SCAN_ITEMS; ++j) {
        const int i = base + j;
        if (i < NN) offs[i] = excl;
        excl += v[j];
    }
    if (t == SCAN_BLOCK - 1) partials[bid] = s[t];
}

// ---------------- scan stage 2+3 fused: finalize offs + bcursor ----------------
__global__ __launch_bounds__(256) void scan23_kernel(
    int* __restrict__ offs, const int* __restrict__ partials, int* __restrict__ bcursor)
{
    __shared__ int sp[128];
    const int t = threadIdx.x, bid = blockIdx.x;
    if (t < 128) sp[t] = (t < NB1) ? partials[t] : 0;
    __syncthreads();
    int add = 0;
    for (int j = 0; j < bid; ++j) add += sp[j];   // uniform broadcast loop, <=97 iters
    const int base = bid * SCAN_TILE + t * SCAN_ITEMS;
    #pragma unroll
    for (int j = 0; j < SCAN_ITEMS; ++j) {
        const int i = base + j;
        if (i < NN) {
            const int o = offs[i] + add;
            offs[i] = o;
            if ((i & (BNODES - 1)) == 0) bcursor[i >> BSHIFT] = o;
        }
    }
}

// ---------------- partition: edges -> bucket-grouped staging (verified R9) ----------
__global__ __launch_bounds__(PTHREADS) void partition_kernel(
    const int* __restrict__ src, const int* __restrict__ dst,
    int* __restrict__ bcursor, unsigned* __restrict__ staging)
{
    __shared__ unsigned stage[PCHUNK];   // 32 KB
    __shared__ int gpos[PCHUNK];         // 32 KB
    __shared__ int lh[NB];
    __shared__ int lcur[NB];
    __shared__ int gbase[NB];
    __shared__ int wtot[16];
    const int t = threadIdx.x;
    const int lane = t & 63;
    const int wid  = t >> 6;
    const int cbase = blockIdx.x * PCHUNK;
    const int cnt = min(PCHUNK, NE - cbase);

    for (int i = t; i < NB; i += PTHREADS) lh[i] = 0;
    __syncthreads();

    unsigned ent[PEPT];
    int bkt[PEPT];
    #pragma unroll
    for (int j = 0; j < PEPT; ++j) {
        const int idx = t + j * PTHREADS;
        if (idx < cnt) {
            const int s_ = src[cbase + idx];
            const int d_ = dst[cbase + idx];
            bkt[j] = s_ >> BSHIFT;
            ent[j] = (unsigned)d_ | ((unsigned)(s_ & (BNODES - 1)) << 17);
            atomicAdd(&lh[bkt[j]], 1);
        } else bkt[j] = -1;
    }
    __syncthreads();

    const int hv = (t < NB) ? lh[t] : 0;
    int incl = hv;
    #pragma unroll
    for (int off = 1; off < 64; off <<= 1) {
        const int n = __shfl_up(incl, off);
        if (lane >= off) incl += n;
    }
    if (lane == 63) wtot[wid] = incl;
    __syncthreads();
    if (wid == 0 && lane < 16) {
        const int v = wtot[lane];
        int s2 = v;
        #pragma unroll
        for (int off = 1; off < 16; off <<= 1) {
            const int n = __shfl_up(s2, off);
            if (lane >= off) s2 += n;
        }
        wtot[lane] = s2 - v;    // exclusive wave offsets
    }
    __syncthreads();
    if (t < NB) {
        const int excl = incl - hv + wtot[wid];
        lh[t]   = excl;
        lcur[t] = excl;
        gbase[t] = (hv > 0) ? atomicAdd(&bcursor[t], hv) : 0;
    }
    __syncthreads();

    #pragma unroll
    for (int j = 0; j < PEPT; ++j) {
        if (bkt[j] >= 0) {
            const int lp = atomicAdd(&lcur[bkt[j]], 1);
            stage[lp] = ent[j];
            gpos[lp]  = gbase[bkt[j]] + (lp - lh[bkt[j]]);
        }
    }
    __syncthreads();

    for (int i = t; i < cnt; i += PTHREADS)
        staging[gpos[i]] = stage[i];
}

// ------ bucket-resident gather + MLP + heads: LDS sort replaces sdst round-trip -----
__global__ __launch_bounds__(512) void gather_bucket_kernel(
    const __half* __restrict__ h16,
    const int* __restrict__ offs,
    const unsigned* __restrict__ staging,
    const float* __restrict__ Wf1, const float* __restrict__ bf1,
    const float* __restrict__ Wf2, const float* __restrict__ bf2,
    const float* __restrict__ Ws1, const float* __restrict__ bs1,
    const float* __restrict__ Ws2, const float* __restrict__ bs2,
    const float* __restrict__ Wt1, const float* __restrict__ bt1,
    const float* __restrict__ Wt2, const float* __restrict__ bt2,
    float* __restrict__ out_scores, float* __restrict__ out_types)
{
    __shared__ int ldst[GCAP];           // 10 KB: node-ordered edge targets (this half)
    __shared__ int soffs[65];
    __shared__ int lcur[64];
    __shared__ __align__(16) float sa[8][H];
    __shared__ __align__(16) float sb[8][H];

    const int t      = threadIdx.x;
    const int nbase  = blockIdx.x * 64;          // half-bucket node base
    const int half   = blockIdx.x & 1;
    const int bucket = blockIdx.x >> 1;

    if (t < 65) {
        const int g = nbase + t;
        soffs[t] = (g < NN) ? offs[g] : NE;
    }
    __syncthreads();
    const int base0 = soffs[0];
    if (t < 64) lcur[t] = soffs[t] - base0;

    // full partition-bucket staging range (this block filters its half)
    const int bb = bucket * BNODES;              // always < NN
    const int s_begin = offs[bb];
    const int ge = bb + BNODES;
    const int s_end = (ge < NN) ? offs[ge] : NE;
    __syncthreads();

    // LDS counting-scatter (logic identical to verified bucket_sort, filtered by half)
    for (int i = t; i < s_end - s_begin; i += 512) {
        const unsigned ev = staging[s_begin + i];
        const int loc = (int)(ev >> 17);
        if ((loc >> 6) == half) {
            const int lp = atomicAdd(&lcur[loc & 63], 1);
            ldst[lp] = (int)(ev & 0x1FFFFu);
        }
    }
    __syncthreads();

    // per-wave gather + MLP (verified R9 inner structure; indices from LDS)
    const int w = t >> 6;
    const int f = t & 63;

    for (int it = 0; it < 8; ++it) {
        const int n    = it * 8 + w;             // wave-uniform
        const int node = nbase + n;
        if (node >= NN) continue;                // wave-uniform

        const int sl  = soffs[n] - base0;
        const int deg = soffs[n + 1] - soffs[n];
        const float selfv = __half2float(h16[((size_t)node << 6) + f]);

        float acc = 0.0f;
        int jj = 0;
        for (; jj + 16 <= deg; jj += 16) {       // 16 uniform rows in flight
            __half hv[16];
            #pragma unroll
            for (int u = 0; u < 16; ++u) {
                const int d = ldst[sl + jj + u];     // LDS broadcast
                hv[u] = h16[((size_t)d << 6) + f];
            }
            #pragma unroll
            for (int u = 0; u < 16; ++u)
                acc += __half2float(hv[u]);
        }
        if (jj + 8 <= deg) {
            __half hv[8];
            #pragma unroll
            for (int u = 0; u < 8; ++u) {
                const int d = ldst[sl + jj + u];
                hv[u] = h16[((size_t)d << 6) + f];
            }
            #pragma unroll
            for (int u = 0; u < 8; ++u)
                acc += __half2float(hv[u]);
            jj += 8;
        }
        for (; jj < deg; ++jj) {
            const int d = ldst[sl + jj];
            acc += __half2float(h16[((size_t)d << 6) + f]);
        }

        const float inv = 1.0f / fmaxf((float)deg, 1.0f);
        sa[w][f] = selfv + acc * inv;

        // layer f1 (float4 broadcast reads; same summation order as scalar loop)
        {
            float a2 = bf1[f];
            const float4* xr = (const float4*)sa[w];
            #pragma unroll 4
            for (int k4 = 0; k4 < 16; ++k4) {
                const float4 xv = xr[k4];
                const int k = k4 * 4;
                a2 = fmaf(xv.x, Wf1[(k + 0) * H + f], a2);
                a2 = fmaf(xv.y, Wf1[(k + 1) * H + f], a2);
                a2 = fmaf(xv.z, Wf1[(k + 2) * H + f], a2);
                a2 = fmaf(xv.w, Wf1[(k + 3) * H + f], a2);
            }
            sb[w][f] = fmaxf(a2, 0.0f);
        }
        // layer f2
        {
            float a2 = bf2[f];
            const float4* xr = (const float4*)sb[w];
            #pragma unroll 4
            for (int k4 = 0; k4 < 16; ++k4) {
                const float4 xv = xr[k4];
                const int k = k4 * 4;
                a2 = fmaf(xv.x, Wf2[(k + 0) * H + f], a2);
                a2 = fmaf(xv.y, Wf2[(k + 1) * H + f], a2);
                a2 = fmaf(xv.z, Wf2[(k + 2) * H + f], a2);
                a2 = fmaf(xv.w, Wf2[(k + 3) * H + f], a2);
            }
            sa[w][f] = fmaxf(a2, 0.0f);
        }
        // heads stage 1
        {
            const float4* xr = (const float4*)sa[w];
            if (f < 32) {
                float a2 = bs1[f];
                #pragma unroll 4
                for (int k4 = 0; k4 < 16; ++k4) {
                    const float4 xv = xr[k4];
                    const int k = k4 * 4;
                    a2 = fmaf(xv.x, Ws1[(k + 0) * 32 + f], a2);
                    a2 = fmaf(xv.y, Ws1[(k + 1) * 32 + f], a2);
                    a2 = fmaf(xv.z, Ws1[(k + 2) * 32 + f], a2);
                    a2 = fmaf(xv.w, Ws1[(k + 3) * 32 + f], a2);
                }
                sb[w][f] = fmaxf(a2, 0.0f);
            } else {
                const int j2 = f - 32;
                float a2 = bt1[j2];
                #pragma unroll 4
                for (int k4 = 0; k4 < 16; ++k4) {
                    const float4 xv = xr[k4];
                    const int k = k4 * 4;
                    a2 = fmaf(xv.x, Wt1[(k + 0) * 32 + j2], a2);
                    a2 = fmaf(xv.y, Wt1[(k + 1) * 32 + j2], a2);
                    a2 = fmaf(xv.z, Wt1[(k + 2) * 32 + j2], a2);
                    a2 = fmaf(xv.w, Wt1[(k + 3) * 32 + j2], a2);
                }
                sb[w][32 + j2] = fmaxf(a2, 0.0f);
            }
        }
        // heads stage 2 (verified shape)
        {
            if (f == 0) {
                float a2 = bs2[0];
                #pragma unroll 8
                for (int j2 = 0; j2 < 32; ++j2)
                    a2 = fmaf(sb[w][j2], Ws2[j2], a2);
                out_scores[node] = a2;
            } else if (f >= 1 && f < 5) {
                const int c = f - 1;
                float a2 = bt2[c];
                #pragma unroll 8
                for (int j2 = 0; j2 < 32; ++j2)
                    a2 = fmaf(sb[w][32 + j2], Wt2[j2 * 4 + c], a2);
                out_types[node * 4 + c] = a2;
            }
        }
    }
}

extern "C" void kernel_launch(void* const* d_in, const int* in_sizes, int n_in,
                              void* d_out, int out_size, void* d_ws, size_t ws_size,
                              hipStream_t stream)
{
    const float* x   = (const float*)d_in[0];
    const int*   adj = (const int*)  d_in[1];   // [2, E]: src = adj[0:E], dst = adj[E:2E]
    const float* W1  = (const float*)d_in[2];
    const float* b1  = (const float*)d_in[3];
    const float* W2  = (const float*)d_in[4];
    const float* b2  = (const float*)d_in[5];
    const float* Wf1 = (const float*)d_in[6];
    const float* bf1 = (const float*)d_in[7];
    const float* Wf2 = (const float*)d_in[8];
    const float* bf2 = (const float*)d_in[9];
    const float* Ws1 = (const float*)d_in[10];
    const float* bs1 = (const float*)d_in[11];
    const float* Ws2 = (const float*)d_in[12];
    const float* bs2 = (const float*)d_in[13];
    const float* Wt1 = (const float*)d_in[14];
    const float* bt1 = (const float*)d_in[15];
    const float* Wt2 = (const float*)d_in[16];
    const float* bt2 = (const float*)d_in[17];

    float* out_scores = (float*)d_out;          // [N]
    float* out_types  = out_scores + NN;        // [N,4]

    // ws: staging [NE u32] | h16 [NN*H half] | counts [NN] | offs [NN] | partials [128]
    //     | bcursor [NB]
    unsigned* staging  = (unsigned*)d_ws;
    __half*   h16      = (__half*)(staging + NE);
    int*      counts   = (int*)(h16 + (size_t)NN * H);
    int*      offs     = counts + NN;
    int*      partials = offs + NN;
    int*      bcursor  = partials + 128;

    const int* src = adj;
    const int* dst = adj + NE;

    hipMemsetAsync(counts, 0, NN * sizeof(int), stream);

    encoder_count_kernel<<<NN / 4, 256, 0, stream>>>(x, W1, b1, W2, b2, src, counts, h16);
    scan1_kernel<<<NB1, SCAN_BLOCK, 0, stream>>>(counts, offs, partials);
    scan23_kernel<<<NB1, SCAN_BLOCK, 0, stream>>>(offs, partials, bcursor);
    partition_kernel<<<NPBLK, PTHREADS, 0, stream>>>(src, dst, bcursor, staging);
    gather_bucket_kernel<<<NB * 2, 512, 0, stream>>>(h16, offs, staging,
                                                     Wf1, bf1, Wf2, bf2,
                                                     Ws1, bs1, Ws2, bs2,
                                                     Wt1, bt1, Wt2, bt2,
                                                     out_scores, out_types);
}

// Round 11
// 545.239 us; speedup vs baseline: 1.1235x; 1.1235x over previous
//
#include <hip/hip_runtime.h>
#include <hip/hip_fp16.h>

#define NN 100000
#define NE 3200000
#define H  64

#define SCAN_BLOCK 256
#define SCAN_ITEMS 4
#define SCAN_TILE  1024
#define NB1 ((NN + SCAN_TILE - 1) / SCAN_TILE)   // 98

#define BSHIFT 7
#define BNODES 128
#define NB ((NN + BNODES - 1) / BNODES)          // 782 partition buckets

#define PTHREADS 1024
#define PCHUNK   12288
#define PEPT     (PCHUNK / PTHREADS)             // 12
#define NPBLK    ((NE + PCHUNK - 1) / PCHUNK)    // 261

#define ECAP 6144                                // per-bucket cap (mean 4096, sd ~64)

// ---------------- encoder + fused edge count (verified R6/R9) ----------------
__global__ __launch_bounds__(256) void encoder_count_kernel(
    const float* __restrict__ x,
    const float* __restrict__ W1, const float* __restrict__ b1,
    const float* __restrict__ W2, const float* __restrict__ b2,
    const int* __restrict__ src, int* __restrict__ counts,
    __half* __restrict__ h16)
{
    __shared__ float sh1[4][H];
    const int tid  = threadIdx.x;
    const int slot = tid >> 6;
    const int f    = tid & 63;
    const int node = blockIdx.x * 4 + slot;      // grid 25000 -> node < NN always

    const int e = blockIdx.x * 256 + tid;        // 6.4M threads cover NE
    if (e < NE) atomicAdd(&counts[src[e]], 1);

    {
        float acc = b1[f];
        #pragma unroll
        for (int k = 0; k < 6; ++k)
            acc = fmaf(x[node * 6 + k], W1[k * H + f], acc);
        sh1[slot][f] = fmaxf(acc, 0.0f);
    }
    __syncthreads();
    {
        float acc = b2[f];
        #pragma unroll 8
        for (int k = 0; k < H; ++k)
            acc = fmaf(sh1[slot][k], W2[k * H + f], acc);
        h16[node * H + f] = __float2half(acc);
    }
}

// ---------------- scan stage 1 (verified R6/R9) ----------------
__global__ __launch_bounds__(256) void scan1_kernel(
    const int* __restrict__ counts, int* __restrict__ offs, int* __restrict__ partials)
{
    __shared__ int s[SCAN_BLOCK];
    const int t = threadIdx.x, bid = blockIdx.x;
    const int base = bid * SCAN_TILE + t * SCAN_ITEMS;
    int v[SCAN_ITEMS];
    int sum = 0;
    #pragma unroll
    for (int j = 0; j < SCAN_ITEMS; ++j) {
        const int i = base + j;
        v[j] = (i < NN) ? counts[i] : 0;
        sum += v[j];
    }
    s[t] = sum;
    __syncthreads();
    for (int off = 1; off < SCAN_BLOCK; off <<= 1) {
        int xv = 0;
        if (t >= off) xv = s[t - off];
        __syncthreads();
        if (t >= off) s[t] += xv;
        __syncthreads();
    }
    int excl = s[t] - sum;
    #pragma unroll
    for (int j = 0; j < SCAN_ITEMS; ++j) {
        const int i = base + j;
        if (i < NN) offs[i] = excl;
        excl += v[j];
    }
    if (t == SCAN_BLOCK - 1) partials[bid] = s[t];
}

// ---------------- scan stage 2+3 fused (verified R10) ----------------
__global__ __launch_bounds__(256) void scan23_kernel(
    int* __restrict__ offs, const int* __restrict__ partials, int* __restrict__ bcursor)
{
    __shared__ int sp[128];
    const int t = threadIdx.x, bid = blockIdx.x;
    if (t < 128) sp[t] = (t < NB1) ? partials[t] : 0;
    __syncthreads();
    int add = 0;
    for (int j = 0; j < bid; ++j) add += sp[j];   // uniform broadcast loop, <=97 iters
    const int base = bid * SCAN_TILE + t * SCAN_ITEMS;
    #pragma unroll
    for (int j = 0; j < SCAN_ITEMS; ++j) {
        const int i = base + j;
        if (i < NN) {
            const int o = offs[i] + add;
            offs[i] = o;
            if ((i & (BNODES - 1)) == 0) bcursor[i >> BSHIFT] = o;
        }
    }
}

// ---------------- partition: edges -> bucket-grouped staging ----------------
// (verified R9 structure; PCHUNK 8192 -> 12288 for ~1-line runs + full co-residency)
__global__ __launch_bounds__(PTHREADS) void partition_kernel(
    const int* __restrict__ src, const int* __restrict__ dst,
    int* __restrict__ bcursor, unsigned* __restrict__ staging)
{
    __shared__ unsigned stage[PCHUNK];   // 48 KB
    __shared__ int gpos[PCHUNK];         // 48 KB
    __shared__ int lh[NB];
    __shared__ int lcur[NB];
    __shared__ int gbase[NB];
    __shared__ int wtot[16];
    const int t = threadIdx.x;
    const int lane = t & 63;
    const int wid  = t >> 6;
    const int cbase = blockIdx.x * PCHUNK;
    const int cnt = min(PCHUNK, NE - cbase);

    for (int i = t; i < NB; i += PTHREADS) lh[i] = 0;
    __syncthreads();

    unsigned ent[PEPT];
    int bkt[PEPT];
    #pragma unroll
    for (int j = 0; j < PEPT; ++j) {
        const int idx = t + j * PTHREADS;
        if (idx < cnt) {
            const int s_ = src[cbase + idx];
            const int d_ = dst[cbase + idx];
            bkt[j] = s_ >> BSHIFT;
            ent[j] = (unsigned)d_ | ((unsigned)(s_ & (BNODES - 1)) << 17);
            atomicAdd(&lh[bkt[j]], 1);
        } else bkt[j] = -1;
    }
    __syncthreads();

    const int hv = (t < NB) ? lh[t] : 0;
    int incl = hv;
    #pragma unroll
    for (int off = 1; off < 64; off <<= 1) {
        const int n = __shfl_up(incl, off);
        if (lane >= off) incl += n;
    }
    if (lane == 63) wtot[wid] = incl;
    __syncthreads();
    if (wid == 0 && lane < 16) {
        const int v = wtot[lane];
        int s2 = v;
        #pragma unroll
        for (int off = 1; off < 16; off <<= 1) {
            const int n = __shfl_up(s2, off);
            if (lane >= off) s2 += n;
        }
        wtot[lane] = s2 - v;    // exclusive wave offsets
    }
    __syncthreads();
    if (t < NB) {
        const int excl = incl - hv + wtot[wid];
        lh[t]   = excl;
        lcur[t] = excl;
        gbase[t] = (hv > 0) ? atomicAdd(&bcursor[t], hv) : 0;
    }
    __syncthreads();

    #pragma unroll
    for (int j = 0; j < PEPT; ++j) {
        if (bkt[j] >= 0) {
            const int lp = atomicAdd(&lcur[bkt[j]], 1);
            stage[lp] = ent[j];
            gpos[lp]  = gbase[bkt[j]] + (lp - lh[bkt[j]]);
        }
    }
    __syncthreads();

    for (int i = t; i < cnt; i += PTHREADS)
        staging[gpos[i]] = stage[i];
}

// ---------------- bucket sort: staging -> node-ordered sdst (verified R6/R9) --------
__global__ __launch_bounds__(1024) void bucket_sort_kernel(
    const unsigned* __restrict__ staging, const int* __restrict__ offs,
    int* __restrict__ sdst)
{
    __shared__ int ldst[ECAP];           // 24 KB
    __shared__ int lcur[BNODES];
    const int t = threadIdx.x;
    const int b = blockIdx.x;
    const int nbase = b * BNODES;
    const int base0 = offs[nbase];
    const int endoff = (b == NB - 1) ? NE : offs[nbase + BNODES];
    const int ecnt = endoff - base0;
    const int nvalid = min(BNODES, NN - nbase);

    if (t < BNODES) lcur[t] = (t < nvalid) ? (offs[nbase + t] - base0) : 0;
    __syncthreads();
    for (int i = t; i < ecnt; i += 1024) {
        const unsigned ev = staging[base0 + i];
        const int lp = atomicAdd(&lcur[(int)(ev >> 17)], 1);
        ldst[lp] = (int)(ev & 0x1FFFFu);
    }
    __syncthreads();
    for (int i = t; i < ecnt; i += 1024)
        sdst[base0 + i] = ldst[i];
}

// ------ fused gather(mean) + MLP + heads (verified R9, byte-identical) ------
__global__ __launch_bounds__(256) void gather_head_kernel(
    const __half* __restrict__ h16,
    const int* __restrict__ counts, const int* __restrict__ offs,
    const int* __restrict__ sdst,
    const float* __restrict__ Wf1, const float* __restrict__ bf1,
    const float* __restrict__ Wf2, const float* __restrict__ bf2,
    const float* __restrict__ Ws1, const float* __restrict__ bs1,
    const float* __restrict__ Ws2, const float* __restrict__ bs2,
    const float* __restrict__ Wt1, const float* __restrict__ bt1,
    const float* __restrict__ Wt2, const float* __restrict__ bt2,
    float* __restrict__ out_scores, float* __restrict__ out_types)
{
    __shared__ float sa[4][H];
    __shared__ float sb[4][H];
    const int tid  = threadIdx.x;
    const int slot = tid >> 6;
    const int f    = tid & 63;
    const int node = blockIdx.x * 4 + slot;   // grid 25000 -> node < NN always

    const int deg   = counts[node];
    const int start = offs[node];

    const float selfv = __half2float(h16[((size_t)node << 6) + f]);  // issued early

    float acc = 0.0f;
    for (int base = 0; base < deg; base += 64) {
        const int m = min(64, deg - base);
        int idx = 0;
        if (base + f < deg) idx = sdst[start + base + f];   // coalesced vector load

        int jj = 0;
        for (; jj + 16 <= m; jj += 16) {                    // 16 uniform rows in flight
            __half hv[16];
            #pragma unroll
            for (int u = 0; u < 16; ++u) {
                const int d = __shfl(idx, jj + u);
                hv[u] = h16[((size_t)d << 6) + f];
            }
            #pragma unroll
            for (int u = 0; u < 16; ++u)
                acc += __half2float(hv[u]);
        }
        if (jj + 8 <= m) {                                  // 8-deep tail
            __half hv[8];
            #pragma unroll
            for (int u = 0; u < 8; ++u) {
                const int d = __shfl(idx, jj + u);
                hv[u] = h16[((size_t)d << 6) + f];
            }
            #pragma unroll
            for (int u = 0; u < 8; ++u)
                acc += __half2float(hv[u]);
            jj += 8;
        }
        for (; jj < m; ++jj) {
            const int d = __shfl(idx, jj);
            acc += __half2float(h16[((size_t)d << 6) + f]);
        }
    }

    const float inv = 1.0f / fmaxf((float)deg, 1.0f);
    sa[slot][f] = selfv + acc * inv;
    __syncthreads();

    {
        float a2 = bf1[f];
        #pragma unroll 8
        for (int k = 0; k < H; ++k)
            a2 = fmaf(sa[slot][k], Wf1[k * H + f], a2);
        sb[slot][f] = fmaxf(a2, 0.0f);
    }
    __syncthreads();

    {
        float a2 = bf2[f];
        #pragma unroll 8
        for (int k = 0; k < H; ++k)
            a2 = fmaf(sb[slot][k], Wf2[k * H + f], a2);
        sa[slot][f] = fmaxf(a2, 0.0f);
    }
    __syncthreads();

    {
        if (f < 32) {
            float a2 = bs1[f];
            #pragma unroll 8
            for (int k = 0; k < H; ++k)
                a2 = fmaf(sa[slot][k], Ws1[k * 32 + f], a2);
            sb[slot][f] = fmaxf(a2, 0.0f);
        } else {
            const int jj = f - 32;
            float a2 = bt1[jj];
            #pragma unroll 8
            for (int k = 0; k < H; ++k)
                a2 = fmaf(sa[slot][k], Wt1[k * 32 + jj], a2);
            sb[slot][32 + jj] = fmaxf(a2, 0.0f);
        }
    }
    __syncthreads();

    {
        if (f == 0) {
            float a2 = bs2[0];
            #pragma unroll 8
            for (int jj = 0; jj < 32; ++jj)
                a2 = fmaf(sb[slot][jj], Ws2[jj], a2);
            out_scores[node] = a2;
        } else if (f >= 1 && f < 5) {
            const int c = f - 1;
            float a2 = bt2[c];
            #pragma unroll 8
            for (int jj = 0; jj < 32; ++jj)
                a2 = fmaf(sb[slot][32 + jj], Wt2[jj * 4 + c], a2);
            out_types[node * 4 + c] = a2;
        }
    }
}

extern "C" void kernel_launch(void* const* d_in, const int* in_sizes, int n_in,
                              void* d_out, int out_size, void* d_ws, size_t ws_size,
                              hipStream_t stream)
{
    const float* x   = (const float*)d_in[0];
    const int*   adj = (const int*)  d_in[1];   // [2, E]: src = adj[0:E], dst = adj[E:2E]
    const float* W1  = (const float*)d_in[2];
    const float* b1  = (const float*)d_in[3];
    const float* W2  = (const float*)d_in[4];
    const float* b2  = (const float*)d_in[5];
    const float* Wf1 = (const float*)d_in[6];
    const float* bf1 = (const float*)d_in[7];
    const float* Wf2 = (const float*)d_in[8];
    const float* bf2 = (const float*)d_in[9];
    const float* Ws1 = (const float*)d_in[10];
    const float* bs1 = (const float*)d_in[11];
    const float* Ws2 = (const float*)d_in[12];
    const float* bs2 = (const float*)d_in[13];
    const float* Wt1 = (const float*)d_in[14];
    const float* bt1 = (const float*)d_in[15];
    const float* Wt2 = (const float*)d_in[16];
    const float* bt2 = (const float*)d_in[17];

    float* out_scores = (float*)d_out;          // [N]
    float* out_types  = out_scores + NN;        // [N,4]

    // ws: staging [NE u32] | h16 [NN*H half] | counts [NN] | offs [NN] | partials [128]
    //     | bcursor [NB] | sdst [NE]
    unsigned* staging  = (unsigned*)d_ws;
    __half*   h16      = (__half*)(staging + NE);
    int*      counts   = (int*)(h16 + (size_t)NN * H);
    int*      offs     = counts + NN;
    int*      partials = offs + NN;
    int*      bcursor  = partials + 128;
    int*      sdst     = bcursor + NB;

    const int* src = adj;
    const int* dst = adj + NE;

    hipMemsetAsync(counts, 0, NN * sizeof(int), stream);

    encoder_count_kernel<<<NN / 4, 256, 0, stream>>>(x, W1, b1, W2, b2, src, counts, h16);
    scan1_kernel<<<NB1, SCAN_BLOCK, 0, stream>>>(counts, offs, partials);
    scan23_kernel<<<NB1, SCAN_BLOCK, 0, stream>>>(offs, partials, bcursor);
    partition_kernel<<<NPBLK, PTHREADS, 0, stream>>>(src, dst, bcursor, staging);
    bucket_sort_kernel<<<NB, 1024, 0, stream>>>(staging, offs, sdst);
    gather_head_kernel<<<NN / 4, 256, 0, stream>>>(h16, counts, offs, sdst,
                                                   Wf1, bf1, Wf2, bf2,
                                                   Ws1, bs1, Ws2, bs2,
                                                   Wt1, bt1, Wt2, bt2,
                                                   out_scores, out_types);
}